// Round 1
// baseline (578.955 us; speedup 1.0000x reference)
//
#include <hip/hip_runtime.h>
#include <cstdint>

// ---------------- problem constants ----------------
#define NTOK   8192        // B*S tokens
#define HDIM   1024        // hidden
#define FDIM   2048        // intermediate
#define NEXP   8
#define RTOT   (2*NTOK)    // routed rows (every token has exactly 2 experts)
#define RPAD   256         // tile-overrun padding rows (256-row tiles)

typedef unsigned short u16;
typedef short   bf16x8 __attribute__((ext_vector_type(8)));
typedef float   f32x4  __attribute__((ext_vector_type(4)));
typedef u16     u16x8  __attribute__((ext_vector_type(8)));

__device__ __forceinline__ u16 f2bf(float v) {
  union { float f; uint32_t u; } a; a.f = v;
  uint32_t r = a.u + 0x7FFFu + ((a.u >> 16) & 1u);   // RNE
  return (u16)(r >> 16);
}
__device__ __forceinline__ float bf2f(u16 b) {
  union { uint32_t u; float f; } a; a.u = ((uint32_t)b) << 16; return a.f;
}

// ---------------- router: logits, top-2 (NO global atomics) ----------------
__global__ void router_kernel(const float* __restrict__ x, const float* __restrict__ gw,
                              float* __restrict__ logits, int* __restrict__ te,
                              float* __restrict__ tw) {
  int gid  = blockIdx.x * blockDim.x + threadIdx.x;
  int t    = gid >> 6;
  int lane = gid & 63;
  const float4* xr = (const float4*)(x + (size_t)t * HDIM);
  float acc[NEXP];
#pragma unroll
  for (int e = 0; e < NEXP; ++e) acc[e] = 0.f;
#pragma unroll
  for (int c = 0; c < 4; ++c) {
    float4 xv = xr[c * 64 + lane];
#pragma unroll
    for (int e = 0; e < NEXP; ++e) {
      float4 wv = ((const float4*)(gw + e * HDIM))[c * 64 + lane];
      acc[e] += xv.x * wv.x + xv.y * wv.y + xv.z * wv.z + xv.w * wv.w;
    }
  }
#pragma unroll
  for (int off = 32; off > 0; off >>= 1)
#pragma unroll
    for (int e = 0; e < NEXP; ++e) acc[e] += __shfl_xor(acc[e], off, 64);

  if (lane == 0) {
#pragma unroll
    for (int e = 0; e < NEXP; ++e) logits[(size_t)t * NEXP + e] = acc[e];
    int e1 = 0;
#pragma unroll
    for (int e = 1; e < NEXP; ++e) if (acc[e] > acc[e1]) e1 = e;
    int e2 = -1;
#pragma unroll
    for (int e = 0; e < NEXP; ++e) {
      if (e == e1) continue;
      if (e2 < 0 || acc[e] > acc[e2]) e2 = e;
    }
    float m  = fmaxf(acc[e1], acc[e2]);
    float p1 = __expf(acc[e1] - m), p2 = __expf(acc[e2] - m);
    float inv = 1.f / (p1 + p2);
    te[t * 2]     = e1;  tw[t * 2]     = p1 * inv;
    te[t * 2 + 1] = e2;  tw[t * 2 + 1] = p2 * inv;
  }
}

// ---------------- fused count+prefix: single block, register histogram ----------------
__global__ void count_prefix_kernel(const int* __restrict__ te, int* __restrict__ offs,
                                    int* __restrict__ cursors) {
  __shared__ int wsum[16][NEXP];
  int cnt[NEXP];
#pragma unroll
  for (int e = 0; e < NEXP; ++e) cnt[e] = 0;
  for (int i = threadIdx.x; i < 2 * NTOK; i += 1024) {
    int v = te[i];
#pragma unroll
    for (int e = 0; e < NEXP; ++e) cnt[e] += (v == e) ? 1 : 0;
  }
#pragma unroll
  for (int off = 32; off > 0; off >>= 1)
#pragma unroll
    for (int e = 0; e < NEXP; ++e) cnt[e] += __shfl_xor(cnt[e], off, 64);
  int wave = threadIdx.x >> 6, lane = threadIdx.x & 63;
  if (lane == 0)
#pragma unroll
    for (int e = 0; e < NEXP; ++e) wsum[wave][e] = cnt[e];
  __syncthreads();
  if (threadIdx.x == 0) {
    int s = 0;
    for (int e = 0; e < NEXP; ++e) {
      int c = 0;
      for (int w = 0; w < 16; ++w) c += wsum[w][e];
      offs[e] = s; cursors[e * 16] = s; s += c;
    }
    offs[NEXP] = s;
  }
}

// ---------------- scatter: wave-aggregated atomics; also writes token->slot map ----------------
__global__ void scatter_kernel(const int* __restrict__ te, const float* __restrict__ tw,
                               int* __restrict__ cursors, int* __restrict__ tok_ids,
                               float* __restrict__ wts, int* __restrict__ slots) {
  int t    = blockIdx.x * blockDim.x + threadIdx.x;
  int lane = threadIdx.x & 63;
#pragma unroll
  for (int s = 0; s < 2; ++s) {
    int   e = te[t * 2 + s];
    float w = tw[t * 2 + s];
    int pos = 0;
#pragma unroll
    for (int e0 = 0; e0 < NEXP; ++e0) {
      unsigned long long m = __ballot(e == e0);
      if (e == e0) {
        int leader = __ffsll((unsigned long long)m) - 1;
        int rank   = __popcll(m & ((1ull << lane) - 1ull));
        int b = 0;
        if (lane == leader) b = atomicAdd(&cursors[e0 * 16], (int)__popcll(m));
        b = __shfl(b, leader, 64);
        pos = b + rank;
      }
    }
    tok_ids[pos] = t;
    wts[pos] = w;
    slots[t * 2 + s] = pos;
  }
}

// ---------------- gather + cast X rows to bf16 (expert-sorted) ----------------
__global__ void gather_cast_kernel(const float* __restrict__ x, const int* __restrict__ tok_ids,
                                   u16* __restrict__ Xg) {
  int j = blockIdx.x;
  int t = tok_ids[j];
  float4 v = ((const float4*)(x + (size_t)t * HDIM))[threadIdx.x];
  ushort4 o;
  o.x = f2bf(v.x); o.y = f2bf(v.y); o.z = f2bf(v.z); o.w = f2bf(v.w);
  ((ushort4*)(Xg + (size_t)j * HDIM))[threadIdx.x] = o;
}

// ---------------- fused weight prep: [E][K][N] f32 -> [E][N][K] bf16, all 3 matrices ----------------
__global__ __launch_bounds__(256)
void prep_weights_kernel(const float* __restrict__ Wg, const float* __restrict__ Wu,
                         const float* __restrict__ Wd, u16* __restrict__ Wgt,
                         u16* __restrict__ Wut, u16* __restrict__ Wdt) {
  __shared__ float tile[64 * 65];
  const int mat = blockIdx.z >> 3;
  const int e   = blockIdx.z & 7;
  const int K   = (mat < 2) ? HDIM : FDIM;
  const int N   = (mat < 2) ? FDIM : HDIM;
  const float* src = ((mat == 0) ? Wg : (mat == 1) ? Wu : Wd) + (size_t)e * K * N;
  u16*         dst = ((mat == 0) ? Wgt : (mat == 1) ? Wut : Wdt) + (size_t)e * K * N;
  const int tn = (mat < 2) ? blockIdx.x : blockIdx.y;
  const int tk = (mat < 2) ? blockIdx.y : blockIdx.x;
  const int k0 = tk * 64, n0 = tn * 64;

  const int r  = threadIdx.x >> 2;
  const int c4 = threadIdx.x & 3;
#pragma unroll
  for (int i = 0; i < 4; ++i) {
    int c = (c4 + i * 4) * 4;
    float4 v = *(const float4*)(src + (size_t)(k0 + r) * N + n0 + c);
    tile[r * 65 + c]     = v.x;
    tile[r * 65 + c + 1] = v.y;
    tile[r * 65 + c + 2] = v.z;
    tile[r * 65 + c + 3] = v.w;
  }
  __syncthreads();

  const int kq = threadIdx.x & 7;
  const int nr = threadIdx.x >> 3;
#pragma unroll
  for (int p = 0; p < 2; ++p) {
    int n = p * 32 + nr;
    u16x8 pk;
#pragma unroll
    for (int j = 0; j < 8; ++j)
      pk[j] = f2bf(tile[(kq * 8 + j) * 65 + n]);
    *(u16x8*)(dst + (size_t)(n0 + n) * K + k0 + kq * 8) = pk;
  }
}

// ================= pipelined 256-row GEMM machinery =================
// LDS layout: elem (row,k) at row*64 + (k ^ ((row&7)<<3)); staging pre-swizzles the
// GLOBAL source address so the LDS destination stays linear (both-sides involution).

#define BARRIER()  asm volatile("s_barrier" ::: "memory")
#define SCHEDB()   __builtin_amdgcn_sched_barrier(0)
#define WAITVM(n)  asm volatile("s_waitcnt vmcnt(" #n ")" ::: "memory")

// stage one 128-row x 64-k bf16 half-tile; 512 threads; 2 global_load_lds / thread
__device__ __forceinline__ void stage_half(const u16* __restrict__ src, int ld,
                                           u16* __restrict__ lds, int wave, int lane) {
#pragma unroll
  for (int s = 0; s < 2; ++s) {
    const int base = (s * 8 + wave) << 9;        // wave-uniform elem offset
    const int flat = base + (lane << 3);
    const int row  = flat >> 6;
    const int km   = (flat & 63) ^ ((row & 7) << 3);
    __builtin_amdgcn_global_load_lds(
        (const __attribute__((address_space(1))) uint32_t*)(src + (size_t)row * ld + km),
        (__attribute__((address_space(3))) uint32_t*)(lds + base),
        16, 0, 0);
  }
}

// read the 8 A fragments of one m-half (MH) from a 256-row LDS buffer
template<int MH>
__device__ __forceinline__ void rd_a(const u16* __restrict__ buf, bf16x8 (&aH)[2][4],
                                     int wm, int l15, int quad) {
#pragma unroll
  for (int k2 = 0; k2 < 2; ++k2)
#pragma unroll
    for (int im = 0; im < 4; ++im) {
      const int r  = MH * 128 + wm * 64 + im * 16 + l15;
      const int kq = (k2 * 32 + quad * 8) ^ ((r & 7) << 3);
      aH[k2][im] = *(const bf16x8*)(buf + r * 64 + kq);
    }
}

// read 4 B fragments (2 n-frags x 2 k-slices) starting at row rb of an LDS buffer
__device__ __forceinline__ void rd_b(const u16* __restrict__ buf, int rb, bf16x8 (&bb)[2][2],
                                     int l15, int quad) {
#pragma unroll
  for (int k2 = 0; k2 < 2; ++k2)
#pragma unroll
    for (int in = 0; in < 2; ++in) {
      const int r  = rb + in * 16 + l15;
      const int kq = (k2 * 32 + quad * 8) ^ ((r & 7) << 3);
      bb[k2][in] = *(const bf16x8*)(buf + r * 64 + kq);
    }
}

// 16 MFMA: 4 m-frags x 2 n-frags x 2 k-slices
__device__ __forceinline__ void mm16(const bf16x8 (&aH)[2][4], const bf16x8 (&bb)[2][2],
                                     f32x4 (&ac)[4][2]) {
#pragma unroll
  for (int k2 = 0; k2 < 2; ++k2)
#pragma unroll
    for (int im = 0; im < 4; ++im)
#pragma unroll
      for (int in = 0; in < 2; ++in)
        ac[im][in] = __builtin_amdgcn_mfma_f32_16x16x32_bf16(aH[k2][im], bb[k2][in],
                                                             ac[im][in], 0, 0, 0);
}

// ---------------- GEMM1: G = silu(Xg @ WgT^T) * (Xg @ WuT^T) ----------------
// BM=256 rows, 128 cols of EACH of Wg,Wu. 512 thr / 8 waves (2M x 4N).
// 4 phases/K-tile: {g.mh0, u.mh0, g.mh1, u.mh1}; counted vmcnt(4); raw barriers.
__global__ __launch_bounds__(512, 2)
void gemm1_kernel(const u16* __restrict__ Xg, const u16* __restrict__ Wgt,
                  const u16* __restrict__ Wut, const int* __restrict__ offs,
                  u16* __restrict__ G) {
  const int e     = blockIdx.z;
  const int rbase = offs[e];
  const int rows  = offs[e + 1] - rbase;
  const int row0  = blockIdx.y * 256;
  if (row0 >= rows) return;
  const int n0    = blockIdx.x * 128;

  __shared__ __align__(16) u16 As [2][256 * 64];   // 64 KB
  __shared__ __align__(16) u16 Bgs[2][128 * 64];   // 32 KB
  __shared__ __align__(16) u16 Bus[2][128 * 64];   // 32 KB

  const int tid  = threadIdx.x;
  const int wave = tid >> 6;
  const int lane = tid & 63;
  const int wm   = wave >> 2, wn = wave & 3;
  const int l15  = lane & 15, quad = lane >> 4;

  const u16* Ap  = Xg  + (size_t)(rbase + row0) * HDIM;
  const u16* Bgp = Wgt + (size_t)e * FDIM * HDIM + (size_t)n0 * HDIM;
  const u16* Bup = Wut + (size_t)e * FDIM * HDIM + (size_t)n0 * HDIM;

  f32x4 accg[2][4][2], accu[2][4][2];
#pragma unroll
  for (int h = 0; h < 2; ++h)
#pragma unroll
    for (int i = 0; i < 4; ++i)
#pragma unroll
      for (int j = 0; j < 2; ++j) { accg[h][i][j] = (f32x4)0.f; accu[h][i][j] = (f32x4)0.f; }

  bf16x8 aH[2][4], bg[2][2], bu[2][2];

  // prologue: tile 0 units in order A-lo, B-G, B-U, A-hi  (8 loads/wave)
  stage_half(Ap,                         HDIM, As[0],            wave, lane); SCHEDB();
  stage_half(Bgp,                        HDIM, Bgs[0],           wave, lane); SCHEDB();
  stage_half(Bup,                        HDIM, Bus[0],           wave, lane); SCHEDB();
  stage_half(Ap + (size_t)128 * HDIM,    HDIM, As[0] + 128 * 64, wave, lane);
  WAITVM(4); BARRIER(); SCHEDB();      // forces A-lo,B-G done; B-U,A-hi in flight

  const int NT = HDIM / 64;            // 16 K-tiles
  int b = 0;
  for (int kt = 0; kt < NT - 1; ++kt) {
    const u16* An  = Ap  + 64;
    const u16* Bgn = Bgp + 64;
    const u16* Bun = Bup + 64;
    const u16* Ac  = As[b];  const u16* Bgc = Bgs[b]; const u16* Buc = Bus[b];
    u16* Ax = As[b ^ 1]; u16* Bgx = Bgs[b ^ 1]; u16* Bux = Bus[b ^ 1];

    // P1: gate x mh0 ; issue A-lo(t+1) ; vmcnt forces B-U(t)
    rd_a<0>(Ac, aH, wm, l15, quad);
    rd_b(Bgc, wn * 32, bg, l15, quad);
    stage_half(An, HDIM, Ax, wave, lane);
    WAITVM(4); BARRIER(); SCHEDB();
    __builtin_amdgcn_s_setprio(1);
    mm16(aH, bg, accg[0]);
    __builtin_amdgcn_s_setprio(0);
    BARRIER(); SCHEDB();

    // P2: up x mh0 ; issue B-G(t+1) ; vmcnt forces A-hi(t)
    rd_b(Buc, wn * 32, bu, l15, quad);
    stage_half(Bgn, HDIM, Bgx, wave, lane);
    WAITVM(4); BARRIER(); SCHEDB();
    __builtin_amdgcn_s_setprio(1);
    mm16(aH, bu, accu[0]);
    __builtin_amdgcn_s_setprio(0);
    BARRIER(); SCHEDB();

    // P3: gate x mh1 ; issue B-U(t+1) ; no wait
    rd_a<1>(Ac, aH, wm, l15, quad);
    stage_half(Bun, HDIM, Bux, wave, lane);
    BARRIER(); SCHEDB();
    __builtin_amdgcn_s_setprio(1);
    mm16(aH, bg, accg[1]);
    __builtin_amdgcn_s_setprio(0);
    BARRIER(); SCHEDB();

    // P4: up x mh1 ; issue A-hi(t+1) ; vmcnt forces A-lo(t+1),B-G(t+1)
    stage_half(An + (size_t)128 * HDIM, HDIM, Ax + 128 * 64, wave, lane);
    WAITVM(4); BARRIER(); SCHEDB();
    __builtin_amdgcn_s_setprio(1);
    mm16(aH, bu, accu[1]);
    __builtin_amdgcn_s_setprio(0);
    BARRIER(); SCHEDB();

    Ap = An; Bgp = Bgn; Bup = Bun; b ^= 1;
  }
  // final K-tile (no prefetch)
  {
    const u16* Ac = As[b]; const u16* Bgc = Bgs[b]; const u16* Buc = Bus[b];
    rd_a<0>(Ac, aH, wm, l15, quad);
    rd_b(Bgc, wn * 32, bg, l15, quad);
    WAITVM(2); BARRIER(); SCHEDB();          // forces B-U; A-hi still in flight
    mm16(aH, bg, accg[0]);
    rd_b(Buc, wn * 32, bu, l15, quad);
    mm16(aH, bu, accu[0]);
    WAITVM(0); BARRIER(); SCHEDB();          // forces A-hi
    rd_a<1>(Ac, aH, wm, l15, quad);
    mm16(aH, bg, accg[1]);
    mm16(aH, bu, accu[1]);
  }

  // epilogue: silu(g)*u -> bf16 G[row][n]
#pragma unroll
  for (int mh = 0; mh < 2; ++mh)
#pragma unroll
    for (int im = 0; im < 4; ++im)
#pragma unroll
      for (int rr = 0; rr < 4; ++rr) {
        int lrow = row0 + mh * 128 + wm * 64 + im * 16 + quad * 4 + rr;
        if (lrow < rows) {
          size_t grow = (size_t)(rbase + lrow);
#pragma unroll
          for (int in = 0; in < 2; ++in) {
            float g = accg[mh][im][in][rr];
            float u = accu[mh][im][in][rr];
            float val = g / (1.f + __expf(-g)) * u;
            G[grow * FDIM + n0 + wn * 32 + in * 16 + l15] = f2bf(val);
          }
        }
      }
}

// ---------------- GEMM2: Y[grow] = w[grow] * (G[grow] @ Wd^T) ----------------
// BM=256 x BN=128, 512 thr / 8 waves. 2 phases/K-tile: {mh0, mh1}.
// Issue A-lo+B @P1 (vmcnt(4) forces A-hi(t)), A-hi @P2 (vmcnt(2) forces next A-lo,B).
__global__ __launch_bounds__(512, 2)
void gemm2_kernel(const u16* __restrict__ G, const u16* __restrict__ Wdt,
                  const int* __restrict__ offs, const float* __restrict__ wts,
                  u16* __restrict__ Y) {
  const int e     = blockIdx.z;
  const int rbase = offs[e];
  const int rows  = offs[e + 1] - rbase;
  const int row0  = blockIdx.y * 256;
  if (row0 >= rows) return;
  const int n0    = blockIdx.x * 128;

  __shared__ __align__(16) u16 As[2][256 * 64];    // 64 KB
  __shared__ __align__(16) u16 Bs[2][128 * 64];    // 32 KB

  const int tid  = threadIdx.x;
  const int wave = tid >> 6;
  const int lane = tid & 63;
  const int wm   = wave >> 2, wn = wave & 3;
  const int l15  = lane & 15, quad = lane >> 4;

  const u16* Ap = G   + (size_t)(rbase + row0) * FDIM;
  const u16* Bp = Wdt + (size_t)e * HDIM * FDIM + (size_t)n0 * FDIM;

  f32x4 acc[2][4][2];
#pragma unroll
  for (int h = 0; h < 2; ++h)
#pragma unroll
    for (int i = 0; i < 4; ++i)
#pragma unroll
      for (int j = 0; j < 2; ++j) acc[h][i][j] = (f32x4)0.f;

  bf16x8 aH[2][4], bb[2][2];

  // prologue: A-lo, B, A-hi of tile 0
  stage_half(Ap,                      FDIM, As[0],            wave, lane); SCHEDB();
  stage_half(Bp,                      FDIM, Bs[0],            wave, lane); SCHEDB();
  stage_half(Ap + (size_t)128 * FDIM, FDIM, As[0] + 128 * 64, wave, lane);
  WAITVM(2); BARRIER(); SCHEDB();      // forces A-lo,B; A-hi in flight

  const int NT = FDIM / 64;            // 32 K-tiles
  int b = 0;
  for (int kt = 0; kt < NT - 1; ++kt) {
    const u16* An = Ap + 64;
    const u16* Bn = Bp + 64;
    const u16* Ac = As[b]; const u16* Bc = Bs[b];
    u16* Ax = As[b ^ 1]; u16* Bx = Bs[b ^ 1];

    // P1: mh0 ; issue A-lo(t+1)+B(t+1) ; vmcnt forces A-hi(t)
    rd_a<0>(Ac, aH, wm, l15, quad);
    rd_b(Bc, wn * 32, bb, l15, quad);
    stage_half(An, FDIM, Ax, wave, lane); SCHEDB();
    stage_half(Bn, FDIM, Bx, wave, lane);
    WAITVM(4); BARRIER(); SCHEDB();
    __builtin_amdgcn_s_setprio(1);
    mm16(aH, bb, acc[0]);
    __builtin_amdgcn_s_setprio(0);
    BARRIER(); SCHEDB();

    // P2: mh1 ; issue A-hi(t+1) ; vmcnt forces A-lo(t+1),B(t+1)
    rd_a<1>(Ac, aH, wm, l15, quad);
    stage_half(An + (size_t)128 * FDIM, FDIM, Ax + 128 * 64, wave, lane);
    WAITVM(2); BARRIER(); SCHEDB();
    __builtin_amdgcn_s_setprio(1);
    mm16(aH, bb, acc[1]);
    __builtin_amdgcn_s_setprio(0);
    BARRIER(); SCHEDB();

    Ap = An; Bp = Bn; b ^= 1;
  }
  // final K-tile
  {
    const u16* Ac = As[b]; const u16* Bc = Bs[b];
    rd_a<0>(Ac, aH, wm, l15, quad);
    rd_b(Bc, wn * 32, bb, l15, quad);
    mm16(aH, bb, acc[0]);
    WAITVM(0); BARRIER(); SCHEDB();          // forces A-hi
    rd_a<1>(Ac, aH, wm, l15, quad);
    mm16(aH, bb, acc[1]);
  }

  // epilogue: weighted bf16 store
#pragma unroll
  for (int mh = 0; mh < 2; ++mh)
#pragma unroll
    for (int im = 0; im < 4; ++im)
#pragma unroll
      for (int rr = 0; rr < 4; ++rr) {
        int lrow = row0 + mh * 128 + wm * 64 + im * 16 + quad * 4 + rr;
        if (lrow < rows) {
          int grow = rbase + lrow;
          float w  = wts[grow];
          u16* yrow = Y + (size_t)grow * HDIM + n0 + wn * 32 + l15;
#pragma unroll
          for (int in = 0; in < 2; ++in)
            yrow[in * 16] = f2bf(acc[mh][im][in][rr] * w);
        }
      }
}

// ---------------- combine: out[t] = Y[slot0(t)] + Y[slot1(t)] ----------------
__global__ void combine_kernel(const u16* __restrict__ Y, const int* __restrict__ slots,
                               float* __restrict__ out) {
  int t  = blockIdx.x;
  int s1 = slots[2 * t], s2 = slots[2 * t + 1];
  ushort4 a = ((const ushort4*)(Y + (size_t)s1 * HDIM))[threadIdx.x];
  ushort4 b = ((const ushort4*)(Y + (size_t)s2 * HDIM))[threadIdx.x];
  float4 o;
  o.x = bf2f(a.x) + bf2f(b.x);
  o.y = bf2f(a.y) + bf2f(b.y);
  o.z = bf2f(a.z) + bf2f(b.z);
  o.w = bf2f(a.w) + bf2f(b.w);
  ((float4*)(out + (size_t)t * HDIM))[threadIdx.x] = o;
}

// ---------------- launch ----------------
extern "C" void kernel_launch(void* const* d_in, const int* in_sizes, int n_in,
                              void* d_out, int out_size, void* d_ws, size_t ws_size,
                              hipStream_t stream) {
  const float* x  = (const float*)d_in[0];   // [2,4096,1024]
  const float* gw = (const float*)d_in[1];   // [8,1024]
  const float* Wg = (const float*)d_in[2];   // [8,1024,2048]
  const float* Wu = (const float*)d_in[3];   // [8,1024,2048]
  const float* Wd = (const float*)d_in[4];   // [8,2048,1024]

  float* out    = (float*)d_out;             // [8192,1024]
  float* logits = out + (size_t)NTOK * HDIM; // [8192,8]

  char* p = (char*)d_ws;
  u16* Wgt = (u16*)p;  p += (size_t)NEXP * FDIM * HDIM * 2;            // [E][F][H] bf16
  u16* Wut = (u16*)p;  p += (size_t)NEXP * FDIM * HDIM * 2;
  u16* Wdt = (u16*)p;  p += (size_t)NEXP * HDIM * FDIM * 2;            // [E][H][F] bf16
  u16* Xg  = (u16*)p;  p += (size_t)(RTOT + RPAD) * HDIM * 2;          // gathered bf16 rows
  u16* G   = (u16*)p;  p += (size_t)(RTOT + RPAD) * FDIM * 2;          // silu(g)*u, bf16
  int*   tok_ids = (int*)p;   p += (RTOT + RPAD) * 4;
  float* wts     = (float*)p; p += (RTOT + RPAD) * 4;
  int*   te      = (int*)p;   p += NTOK * 2 * 4;
  float* tw      = (float*)p; p += NTOK * 2 * 4;
  int*   slots   = (int*)p;   p += NTOK * 2 * 4;
  int*   offs    = (int*)p;   p += (NEXP + 1) * 4;
  int*   cursors = (int*)p;   p += NEXP * 16 * 4;                      // 64B-strided

  u16* Y = Xg;   // Xg is dead after gemm1; gemm2's per-row output aliases it

  router_kernel<<<(NTOK * 64) / 256, 256, 0, stream>>>(x, gw, logits, te, tw);
  count_prefix_kernel<<<1, 1024, 0, stream>>>(te, offs, cursors);
  scatter_kernel<<<NTOK / 256, 256, 0, stream>>>(te, tw, cursors, tok_ids, wts, slots);
  gather_cast_kernel<<<RTOT, 256, 0, stream>>>(x, tok_ids, Xg);

  prep_weights_kernel<<<dim3(32, 16, 24), 256, 0, stream>>>(Wg, Wu, Wd, Wgt, Wut, Wdt);

  gemm1_kernel<<<dim3(FDIM / 128, 64, NEXP), 512, 0, stream>>>(Xg, Wgt, Wut, offs, G);
  gemm2_kernel<<<dim3(HDIM / 128, 64, NEXP), 512, 0, stream>>>(G, Wdt, offs, wts, Y);
  combine_kernel<<<NTOK, 256, 0, stream>>>(Y, slots, out);
}

// Round 2
// 560.543 us; speedup vs baseline: 1.0328x; 1.0328x over previous
//
#include <hip/hip_runtime.h>
#include <cstdint>

// ---------------- problem constants ----------------
#define NTOK   8192        // B*S tokens
#define HDIM   1024        // hidden
#define FDIM   2048        // intermediate
#define NEXP   8
#define RTOT   (2*NTOK)    // routed rows (every token has exactly 2 experts)
#define RPAD   256         // tile-overrun padding rows (256-row tiles)

typedef unsigned short u16;
typedef short   bf16x8 __attribute__((ext_vector_type(8)));
typedef float   f32x4  __attribute__((ext_vector_type(4)));
typedef u16     u16x8  __attribute__((ext_vector_type(8)));

__device__ __forceinline__ u16 f2bf(float v) {
  union { float f; uint32_t u; } a; a.f = v;
  uint32_t r = a.u + 0x7FFFu + ((a.u >> 16) & 1u);   // RNE
  return (u16)(r >> 16);
}
__device__ __forceinline__ float bf2f(u16 b) {
  union { uint32_t u; float f; } a; a.u = ((uint32_t)b) << 16; return a.f;
}

// ---------------- router: logits, top-2 (NO global atomics) ----------------
__global__ void router_kernel(const float* __restrict__ x, const float* __restrict__ gw,
                              float* __restrict__ logits, int* __restrict__ te,
                              float* __restrict__ tw) {
  int gid  = blockIdx.x * blockDim.x + threadIdx.x;
  int t    = gid >> 6;
  int lane = gid & 63;
  const float4* xr = (const float4*)(x + (size_t)t * HDIM);
  float acc[NEXP];
#pragma unroll
  for (int e = 0; e < NEXP; ++e) acc[e] = 0.f;
#pragma unroll
  for (int c = 0; c < 4; ++c) {
    float4 xv = xr[c * 64 + lane];
#pragma unroll
    for (int e = 0; e < NEXP; ++e) {
      float4 wv = ((const float4*)(gw + e * HDIM))[c * 64 + lane];
      acc[e] += xv.x * wv.x + xv.y * wv.y + xv.z * wv.z + xv.w * wv.w;
    }
  }
#pragma unroll
  for (int off = 32; off > 0; off >>= 1)
#pragma unroll
    for (int e = 0; e < NEXP; ++e) acc[e] += __shfl_xor(acc[e], off, 64);

  if (lane == 0) {
#pragma unroll
    for (int e = 0; e < NEXP; ++e) logits[(size_t)t * NEXP + e] = acc[e];
    int e1 = 0;
#pragma unroll
    for (int e = 1; e < NEXP; ++e) if (acc[e] > acc[e1]) e1 = e;
    int e2 = -1;
#pragma unroll
    for (int e = 0; e < NEXP; ++e) {
      if (e == e1) continue;
      if (e2 < 0 || acc[e] > acc[e2]) e2 = e;
    }
    float m  = fmaxf(acc[e1], acc[e2]);
    float p1 = __expf(acc[e1] - m), p2 = __expf(acc[e2] - m);
    float inv = 1.f / (p1 + p2);
    te[t * 2]     = e1;  tw[t * 2]     = p1 * inv;
    te[t * 2 + 1] = e2;  tw[t * 2 + 1] = p2 * inv;
  }
}

// ---------------- fused count+prefix: single block, register histogram ----------------
__global__ void count_prefix_kernel(const int* __restrict__ te, int* __restrict__ offs,
                                    int* __restrict__ cursors) {
  __shared__ int wsum[16][NEXP];
  int cnt[NEXP];
#pragma unroll
  for (int e = 0; e < NEXP; ++e) cnt[e] = 0;
  for (int i = threadIdx.x; i < 2 * NTOK; i += 1024) {
    int v = te[i];
#pragma unroll
    for (int e = 0; e < NEXP; ++e) cnt[e] += (v == e) ? 1 : 0;
  }
#pragma unroll
  for (int off = 32; off > 0; off >>= 1)
#pragma unroll
    for (int e = 0; e < NEXP; ++e) cnt[e] += __shfl_xor(cnt[e], off, 64);
  int wave = threadIdx.x >> 6, lane = threadIdx.x & 63;
  if (lane == 0)
#pragma unroll
    for (int e = 0; e < NEXP; ++e) wsum[wave][e] = cnt[e];
  __syncthreads();
  if (threadIdx.x == 0) {
    int s = 0;
    for (int e = 0; e < NEXP; ++e) {
      int c = 0;
      for (int w = 0; w < 16; ++w) c += wsum[w][e];
      offs[e] = s; cursors[e * 16] = s; s += c;
    }
    offs[NEXP] = s;
  }
}

// ---------------- scatter: wave-aggregated atomics; also writes token->slot map ----------------
__global__ void scatter_kernel(const int* __restrict__ te, const float* __restrict__ tw,
                               int* __restrict__ cursors, int* __restrict__ tok_ids,
                               float* __restrict__ wts, int* __restrict__ slots) {
  int t    = blockIdx.x * blockDim.x + threadIdx.x;
  int lane = threadIdx.x & 63;
#pragma unroll
  for (int s = 0; s < 2; ++s) {
    int   e = te[t * 2 + s];
    float w = tw[t * 2 + s];
    int pos = 0;
#pragma unroll
    for (int e0 = 0; e0 < NEXP; ++e0) {
      unsigned long long m = __ballot(e == e0);
      if (e == e0) {
        int leader = __ffsll((unsigned long long)m) - 1;
        int rank   = __popcll(m & ((1ull << lane) - 1ull));
        int b = 0;
        if (lane == leader) b = atomicAdd(&cursors[e0 * 16], (int)__popcll(m));
        b = __shfl(b, leader, 64);
        pos = b + rank;
      }
    }
    tok_ids[pos] = t;
    wts[pos] = w;
    slots[t * 2 + s] = pos;
  }
}

// ---------------- gather + cast X rows to bf16 (expert-sorted) ----------------
__global__ void gather_cast_kernel(const float* __restrict__ x, const int* __restrict__ tok_ids,
                                   u16* __restrict__ Xg) {
  int j = blockIdx.x;
  int t = tok_ids[j];
  float4 v = ((const float4*)(x + (size_t)t * HDIM))[threadIdx.x];
  ushort4 o;
  o.x = f2bf(v.x); o.y = f2bf(v.y); o.z = f2bf(v.z); o.w = f2bf(v.w);
  ((ushort4*)(Xg + (size_t)j * HDIM))[threadIdx.x] = o;
}

// ---------------- fused weight prep: [E][K][N] f32 -> [E][N][K] bf16, all 3 matrices ----------------
__global__ __launch_bounds__(256)
void prep_weights_kernel(const float* __restrict__ Wg, const float* __restrict__ Wu,
                         const float* __restrict__ Wd, u16* __restrict__ Wgt,
                         u16* __restrict__ Wut, u16* __restrict__ Wdt) {
  __shared__ float tile[64 * 65];
  const int mat = blockIdx.z >> 3;
  const int e   = blockIdx.z & 7;
  const int K   = (mat < 2) ? HDIM : FDIM;
  const int N   = (mat < 2) ? FDIM : HDIM;
  const float* src = ((mat == 0) ? Wg : (mat == 1) ? Wu : Wd) + (size_t)e * K * N;
  u16*         dst = ((mat == 0) ? Wgt : (mat == 1) ? Wut : Wdt) + (size_t)e * K * N;
  const int tn = (mat < 2) ? blockIdx.x : blockIdx.y;
  const int tk = (mat < 2) ? blockIdx.y : blockIdx.x;
  const int k0 = tk * 64, n0 = tn * 64;

  const int r  = threadIdx.x >> 2;
  const int c4 = threadIdx.x & 3;
#pragma unroll
  for (int i = 0; i < 4; ++i) {
    int c = (c4 + i * 4) * 4;
    float4 v = *(const float4*)(src + (size_t)(k0 + r) * N + n0 + c);
    tile[r * 65 + c]     = v.x;
    tile[r * 65 + c + 1] = v.y;
    tile[r * 65 + c + 2] = v.z;
    tile[r * 65 + c + 3] = v.w;
  }
  __syncthreads();

  const int kq = threadIdx.x & 7;
  const int nr = threadIdx.x >> 3;
#pragma unroll
  for (int p = 0; p < 2; ++p) {
    int n = p * 32 + nr;
    u16x8 pk;
#pragma unroll
    for (int j = 0; j < 8; ++j)
      pk[j] = f2bf(tile[(kq * 8 + j) * 65 + n]);
    *(u16x8*)(dst + (size_t)(n0 + n) * K + k0 + kq * 8) = pk;
  }
}

// ================= pipelined 256-row GEMM machinery =================
// LDS layout: elem (row,k) at row*64 + (k ^ ((row&7)<<3)); staging pre-swizzles the
// GLOBAL source address so the LDS destination stays linear (both-sides involution).
// Sync discipline (m201 template): builtin s_barrier (no memory-clobber asm — a
// clobber forces the compiler to drain lgkm/vm counters at every barrier, which
// serializes ds_read vs MFMA), counted vmcnt (never 0 in steady state), ONE
// barrier per phase (full double-buffering makes 1-phase wave slip race-free:
// staging targets buffer b^1, reads target b, MFMA clusters touch no LDS).

#define BARRIER()  __builtin_amdgcn_s_barrier()
#define WAITVM(n)  asm volatile("s_waitcnt vmcnt(" #n ")")

// stage one 128-row x 64-k bf16 half-tile; 512 threads; 2 global_load_lds / thread
__device__ __forceinline__ void stage_half(const u16* __restrict__ src, int ld,
                                           u16* __restrict__ lds, int wave, int lane) {
#pragma unroll
  for (int s = 0; s < 2; ++s) {
    const int base = (s * 8 + wave) << 9;        // wave-uniform elem offset
    const int flat = base + (lane << 3);
    const int row  = flat >> 6;
    const int km   = (flat & 63) ^ ((row & 7) << 3);
    __builtin_amdgcn_global_load_lds(
        (const __attribute__((address_space(1))) uint32_t*)(src + (size_t)row * ld + km),
        (__attribute__((address_space(3))) uint32_t*)(lds + base),
        16, 0, 0);
  }
}

// read the 8 A fragments of one m-half (MH) from a 256-row LDS buffer
template<int MH>
__device__ __forceinline__ void rd_a(const u16* __restrict__ buf, bf16x8 (&aH)[2][4],
                                     int wm, int l15, int quad) {
#pragma unroll
  for (int k2 = 0; k2 < 2; ++k2)
#pragma unroll
    for (int im = 0; im < 4; ++im) {
      const int r  = MH * 128 + wm * 64 + im * 16 + l15;
      const int kq = (k2 * 32 + quad * 8) ^ ((r & 7) << 3);
      aH[k2][im] = *(const bf16x8*)(buf + r * 64 + kq);
    }
}

// read 4 B fragments (2 n-frags x 2 k-slices) starting at row rb of an LDS buffer
__device__ __forceinline__ void rd_b(const u16* __restrict__ buf, int rb, bf16x8 (&bb)[2][2],
                                     int l15, int quad) {
#pragma unroll
  for (int k2 = 0; k2 < 2; ++k2)
#pragma unroll
    for (int in = 0; in < 2; ++in) {
      const int r  = rb + in * 16 + l15;
      const int kq = (k2 * 32 + quad * 8) ^ ((r & 7) << 3);
      bb[k2][in] = *(const bf16x8*)(buf + r * 64 + kq);
    }
}

// 16 MFMA: 4 m-frags x 2 n-frags x 2 k-slices
__device__ __forceinline__ void mm16(const bf16x8 (&aH)[2][4], const bf16x8 (&bb)[2][2],
                                     f32x4 (&ac)[4][2]) {
#pragma unroll
  for (int k2 = 0; k2 < 2; ++k2)
#pragma unroll
    for (int im = 0; im < 4; ++im)
#pragma unroll
      for (int in = 0; in < 2; ++in)
        ac[im][in] = __builtin_amdgcn_mfma_f32_16x16x32_bf16(aH[k2][im], bb[k2][in],
                                                             ac[im][in], 0, 0, 0);
}

// ---------------- GEMM1: G = silu(Xg @ WgT^T) * (Xg @ WuT^T) ----------------
// BM=256 rows, 128 cols of EACH of Wg,Wu. 512 thr / 8 waves (2M x 4N).
// 4 phases/K-tile, ONE barrier each: {reads+stage+vmcnt | barrier | MFMA}.
__global__ __launch_bounds__(512, 2)
void gemm1_kernel(const u16* __restrict__ Xg, const u16* __restrict__ Wgt,
                  const u16* __restrict__ Wut, const int* __restrict__ offs,
                  u16* __restrict__ G) {
  const int e     = blockIdx.z;
  const int rbase = offs[e];
  const int rows  = offs[e + 1] - rbase;
  const int row0  = blockIdx.y * 256;
  if (row0 >= rows) return;
  const int n0    = blockIdx.x * 128;

  __shared__ __align__(16) u16 As [2][256 * 64];   // 64 KB
  __shared__ __align__(16) u16 Bgs[2][128 * 64];   // 32 KB
  __shared__ __align__(16) u16 Bus[2][128 * 64];   // 32 KB

  const int tid  = threadIdx.x;
  const int wave = tid >> 6;
  const int lane = tid & 63;
  const int wm   = wave >> 2, wn = wave & 3;
  const int l15  = lane & 15, quad = lane >> 4;

  const u16* Ap  = Xg  + (size_t)(rbase + row0) * HDIM;
  const u16* Bgp = Wgt + (size_t)e * FDIM * HDIM + (size_t)n0 * HDIM;
  const u16* Bup = Wut + (size_t)e * FDIM * HDIM + (size_t)n0 * HDIM;

  f32x4 accg[2][4][2], accu[2][4][2];
#pragma unroll
  for (int h = 0; h < 2; ++h)
#pragma unroll
    for (int i = 0; i < 4; ++i)
#pragma unroll
      for (int j = 0; j < 2; ++j) { accg[h][i][j] = (f32x4)0.f; accu[h][i][j] = (f32x4)0.f; }

  bf16x8 aH[2][4], bg[2][2], bu[2][2];

  // prologue: tile 0 units in order A-lo, B-G, B-U, A-hi  (8 loads/wave)
  stage_half(Ap,                         HDIM, As[0],            wave, lane);
  stage_half(Bgp,                        HDIM, Bgs[0],           wave, lane);
  stage_half(Bup,                        HDIM, Bus[0],           wave, lane);
  stage_half(Ap + (size_t)128 * HDIM,    HDIM, As[0] + 128 * 64, wave, lane);
  WAITVM(4); BARRIER();                // A-lo,B-G done; B-U,A-hi in flight

  const int NT = HDIM / 64;            // 16 K-tiles
  int b = 0;
  for (int kt = 0; kt < NT - 1; ++kt) {
    const u16* An  = Ap  + 64;
    const u16* Bgn = Bgp + 64;
    const u16* Bun = Bup + 64;
    const u16* Ac  = As[b];  const u16* Bgc = Bgs[b]; const u16* Buc = Bus[b];
    u16* Ax = As[b ^ 1]; u16* Bgx = Bgs[b ^ 1]; u16* Bux = Bus[b ^ 1];

    // P1: gate x mh0 ; issue A-lo(t+1) ; vmcnt forces B-U(t)
    rd_a<0>(Ac, aH, wm, l15, quad);
    rd_b(Bgc, wn * 32, bg, l15, quad);
    stage_half(An, HDIM, Ax, wave, lane);
    WAITVM(4); BARRIER();
    __builtin_amdgcn_s_setprio(1);
    mm16(aH, bg, accg[0]);
    __builtin_amdgcn_s_setprio(0);

    // P2: up x mh0 ; issue B-G(t+1) ; vmcnt forces A-hi(t)
    rd_b(Buc, wn * 32, bu, l15, quad);
    stage_half(Bgn, HDIM, Bgx, wave, lane);
    WAITVM(4); BARRIER();
    __builtin_amdgcn_s_setprio(1);
    mm16(aH, bu, accu[0]);
    __builtin_amdgcn_s_setprio(0);

    // P3: gate x mh1 ; issue B-U(t+1) ; no wait
    rd_a<1>(Ac, aH, wm, l15, quad);
    stage_half(Bun, HDIM, Bux, wave, lane);
    BARRIER();
    __builtin_amdgcn_s_setprio(1);
    mm16(aH, bg, accg[1]);
    __builtin_amdgcn_s_setprio(0);

    // P4: up x mh1 ; issue A-hi(t+1) ; vmcnt forces A-lo(t+1),B-G(t+1)
    stage_half(An + (size_t)128 * HDIM, HDIM, Ax + 128 * 64, wave, lane);
    WAITVM(4); BARRIER();
    __builtin_amdgcn_s_setprio(1);
    mm16(aH, bu, accu[1]);
    __builtin_amdgcn_s_setprio(0);

    Ap = An; Bgp = Bgn; Bup = Bun; b ^= 1;
  }
  // final K-tile (no prefetch)
  {
    const u16* Ac = As[b]; const u16* Bgc = Bgs[b]; const u16* Buc = Bus[b];
    rd_a<0>(Ac, aH, wm, l15, quad);
    rd_b(Bgc, wn * 32, bg, l15, quad);
    WAITVM(2); BARRIER();                    // forces B-U; A-hi still in flight
    mm16(aH, bg, accg[0]);
    rd_b(Buc, wn * 32, bu, l15, quad);
    mm16(aH, bu, accu[0]);
    WAITVM(0); BARRIER();                    // forces A-hi
    rd_a<1>(Ac, aH, wm, l15, quad);
    mm16(aH, bg, accg[1]);
    mm16(aH, bu, accu[1]);
  }

  // epilogue: silu(g)*u -> bf16 G[row][n]
#pragma unroll
  for (int mh = 0; mh < 2; ++mh)
#pragma unroll
    for (int im = 0; im < 4; ++im)
#pragma unroll
      for (int rr = 0; rr < 4; ++rr) {
        int lrow = row0 + mh * 128 + wm * 64 + im * 16 + quad * 4 + rr;
        if (lrow < rows) {
          size_t grow = (size_t)(rbase + lrow);
#pragma unroll
          for (int in = 0; in < 2; ++in) {
            float g = accg[mh][im][in][rr];
            float u = accu[mh][im][in][rr];
            float val = g / (1.f + __expf(-g)) * u;
            G[grow * FDIM + n0 + wn * 32 + in * 16 + l15] = f2bf(val);
          }
        }
      }
}

// ---------------- GEMM2: Y[grow] = w[grow] * (G[grow] @ Wd^T) ----------------
// BM=256 x BN=128, 512 thr / 8 waves. 2 phases/K-tile, ONE barrier each.
__global__ __launch_bounds__(512, 2)
void gemm2_kernel(const u16* __restrict__ G, const u16* __restrict__ Wdt,
                  const int* __restrict__ offs, const float* __restrict__ wts,
                  u16* __restrict__ Y) {
  const int e     = blockIdx.z;
  const int rbase = offs[e];
  const int rows  = offs[e + 1] - rbase;
  const int row0  = blockIdx.y * 256;
  if (row0 >= rows) return;
  const int n0    = blockIdx.x * 128;

  __shared__ __align__(16) u16 As[2][256 * 64];    // 64 KB
  __shared__ __align__(16) u16 Bs[2][128 * 64];    // 32 KB

  const int tid  = threadIdx.x;
  const int wave = tid >> 6;
  const int lane = tid & 63;
  const int wm   = wave >> 2, wn = wave & 3;
  const int l15  = lane & 15, quad = lane >> 4;

  const u16* Ap = G   + (size_t)(rbase + row0) * FDIM;
  const u16* Bp = Wdt + (size_t)e * HDIM * FDIM + (size_t)n0 * FDIM;

  f32x4 acc[2][4][2];
#pragma unroll
  for (int h = 0; h < 2; ++h)
#pragma unroll
    for (int i = 0; i < 4; ++i)
#pragma unroll
      for (int j = 0; j < 2; ++j) acc[h][i][j] = (f32x4)0.f;

  bf16x8 aH[2][4], bb[2][2];

  // prologue: A-lo, B, A-hi of tile 0
  stage_half(Ap,                      FDIM, As[0],            wave, lane);
  stage_half(Bp,                      FDIM, Bs[0],            wave, lane);
  stage_half(Ap + (size_t)128 * FDIM, FDIM, As[0] + 128 * 64, wave, lane);
  WAITVM(2); BARRIER();                // A-lo,B done; A-hi in flight

  const int NT = FDIM / 64;            // 32 K-tiles
  int b = 0;
  for (int kt = 0; kt < NT - 1; ++kt) {
    const u16* An = Ap + 64;
    const u16* Bn = Bp + 64;
    const u16* Ac = As[b]; const u16* Bc = Bs[b];
    u16* Ax = As[b ^ 1]; u16* Bx = Bs[b ^ 1];

    // P1: mh0 ; issue A-lo(t+1)+B(t+1) ; vmcnt forces A-hi(t)
    rd_a<0>(Ac, aH, wm, l15, quad);
    rd_b(Bc, wn * 32, bb, l15, quad);
    stage_half(An, FDIM, Ax, wave, lane);
    stage_half(Bn, FDIM, Bx, wave, lane);
    WAITVM(4); BARRIER();
    __builtin_amdgcn_s_setprio(1);
    mm16(aH, bb, acc[0]);
    __builtin_amdgcn_s_setprio(0);

    // P2: mh1 ; issue A-hi(t+1) ; vmcnt forces A-lo(t+1) AND B(t+1)
    rd_a<1>(Ac, aH, wm, l15, quad);
    stage_half(An + (size_t)128 * FDIM, FDIM, Ax + 128 * 64, wave, lane);
    WAITVM(2); BARRIER();
    __builtin_amdgcn_s_setprio(1);
    mm16(aH, bb, acc[1]);
    __builtin_amdgcn_s_setprio(0);

    Ap = An; Bp = Bn; b ^= 1;
  }
  // final K-tile
  {
    const u16* Ac = As[b]; const u16* Bc = Bs[b];
    rd_a<0>(Ac, aH, wm, l15, quad);
    rd_b(Bc, wn * 32, bb, l15, quad);
    mm16(aH, bb, acc[0]);
    WAITVM(0); BARRIER();                    // forces A-hi
    rd_a<1>(Ac, aH, wm, l15, quad);
    mm16(aH, bb, acc[1]);
  }

  // epilogue: weighted bf16 store
#pragma unroll
  for (int mh = 0; mh < 2; ++mh)
#pragma unroll
    for (int im = 0; im < 4; ++im)
#pragma unroll
      for (int rr = 0; rr < 4; ++rr) {
        int lrow = row0 + mh * 128 + wm * 64 + im * 16 + quad * 4 + rr;
        if (lrow < rows) {
          int grow = rbase + lrow;
          float w  = wts[grow];
          u16* yrow = Y + (size_t)grow * HDIM + n0 + wn * 32 + l15;
#pragma unroll
          for (int in = 0; in < 2; ++in)
            yrow[in * 16] = f2bf(acc[mh][im][in][rr] * w);
        }
      }
}

// ---------------- combine: out[t] = Y[slot0(t)] + Y[slot1(t)] ----------------
__global__ void combine_kernel(const u16* __restrict__ Y, const int* __restrict__ slots,
                               float* __restrict__ out) {
  int t  = blockIdx.x;
  int s1 = slots[2 * t], s2 = slots[2 * t + 1];
  ushort4 a = ((const ushort4*)(Y + (size_t)s1 * HDIM))[threadIdx.x];
  ushort4 b = ((const ushort4*)(Y + (size_t)s2 * HDIM))[threadIdx.x];
  float4 o;
  o.x = bf2f(a.x) + bf2f(b.x);
  o.y = bf2f(a.y) + bf2f(b.y);
  o.z = bf2f(a.z) + bf2f(b.z);
  o.w = bf2f(a.w) + bf2f(b.w);
  ((float4*)(out + (size_t)t * HDIM))[threadIdx.x] = o;
}

// ---------------- launch ----------------
extern "C" void kernel_launch(void* const* d_in, const int* in_sizes, int n_in,
                              void* d_out, int out_size, void* d_ws, size_t ws_size,
                              hipStream_t stream) {
  const float* x  = (const float*)d_in[0];   // [2,4096,1024]
  const float* gw = (const float*)d_in[1];   // [8,1024]
  const float* Wg = (const float*)d_in[2];   // [8,1024,2048]
  const float* Wu = (const float*)d_in[3];   // [8,1024,2048]
  const float* Wd = (const float*)d_in[4];   // [8,2048,1024]

  float* out    = (float*)d_out;             // [8192,1024]
  float* logits = out + (size_t)NTOK * HDIM; // [8192,8]

  char* p = (char*)d_ws;
  u16* Wgt = (u16*)p;  p += (size_t)NEXP * FDIM * HDIM * 2;            // [E][F][H] bf16
  u16* Wut = (u16*)p;  p += (size_t)NEXP * FDIM * HDIM * 2;
  u16* Wdt = (u16*)p;  p += (size_t)NEXP * HDIM * FDIM * 2;            // [E][H][F] bf16
  u16* Xg  = (u16*)p;  p += (size_t)(RTOT + RPAD) * HDIM * 2;          // gathered bf16 rows
  u16* G   = (u16*)p;  p += (size_t)(RTOT + RPAD) * FDIM * 2;          // silu(g)*u, bf16
  int*   tok_ids = (int*)p;   p += (RTOT + RPAD) * 4;
  float* wts     = (float*)p; p += (RTOT + RPAD) * 4;
  int*   te      = (int*)p;   p += NTOK * 2 * 4;
  float* tw      = (float*)p; p += NTOK * 2 * 4;
  int*   slots   = (int*)p;   p += NTOK * 2 * 4;
  int*   offs    = (int*)p;   p += (NEXP + 1) * 4;
  int*   cursors = (int*)p;   p += NEXP * 16 * 4;                      // 64B-strided

  u16* Y = Xg;   // Xg is dead after gemm1; gemm2's per-row output aliases it

  router_kernel<<<(NTOK * 64) / 256, 256, 0, stream>>>(x, gw, logits, te, tw);
  count_prefix_kernel<<<1, 1024, 0, stream>>>(te, offs, cursors);
  scatter_kernel<<<NTOK / 256, 256, 0, stream>>>(te, tw, cursors, tok_ids, wts, slots);
  gather_cast_kernel<<<RTOT, 256, 0, stream>>>(x, tok_ids, Xg);

  prep_weights_kernel<<<dim3(32, 16, 24), 256, 0, stream>>>(Wg, Wu, Wd, Wgt, Wut, Wdt);

  gemm1_kernel<<<dim3(FDIM / 128, 64, NEXP), 512, 0, stream>>>(Xg, Wgt, Wut, offs, G);
  gemm2_kernel<<<dim3(HDIM / 128, 64, NEXP), 512, 0, stream>>>(G, Wdt, offs, wts, Y);
  combine_kernel<<<NTOK, 256, 0, stream>>>(Y, slots, out);
}